// Round 8
// baseline (1273.422 us; speedup 1.0000x reference)
//
#include <hip/hip_runtime.h>
#include <hip/hip_bf16.h>
#include <hip/hip_fp16.h>

#define N_D 256
#define NBLK 832   // edge-pass grid; must match between count/partition kernels

typedef __attribute__((ext_vector_type(8))) short bf16x8;
typedef __attribute__((ext_vector_type(4))) float f32x4;

// f32 -> bf16 round-to-nearest-even (finite inputs)
__device__ __forceinline__ unsigned short f2bf(float f) {
  union { float f; unsigned u; } c; c.f = f;
  unsigned u = c.u;
  return (unsigned short)((u + 0x7fffu + ((u >> 16) & 1u)) >> 16);
}
__device__ __forceinline__ float asf(unsigned u) {
  union { unsigned u; float f; } c; c.u = u;
  return c.f;
}
__device__ __forceinline__ int grp_of(int r, unsigned gmagic) {
  int g = (int)(((unsigned long long)(unsigned)r * gmagic) >> 37);
  return min(g, 7);
}

// ---------- fp32 -> bf16 bulk convert (for x) ----------
__global__ __launch_bounds__(256) void conv_kernel(
    const float* __restrict__ in, unsigned short* __restrict__ out, int n4) {
  int i = blockIdx.x * 256 + threadIdx.x;
  if (i < n4) {
    float4 v = reinterpret_cast<const float4*>(in)[i];
    ushort4 o;
    o.x = f2bf(v.x); o.y = f2bf(v.y); o.z = f2bf(v.z); o.w = f2bf(v.w);
    reinterpret_cast<ushort4*>(out)[i] = o;
  }
}

// ---------- CSR build pass 1: row histogram (XCD-local replicas) ----------
// cnt8[bid%8][r]: blocks with equal bid%8 run on the same XCD (m09 round-robin),
// so each replica's atomic lines stay in one XCD's L2 (no cross-XCD bouncing).
__global__ __launch_bounds__(256) void count_kernel(
    const int* __restrict__ rows, int* __restrict__ cnt8, int* __restrict__ cntT,
    int n_edges, unsigned gmagic, int M) {
  __shared__ int lcnt[8];
  if (threadIdx.x < 8) lcnt[threadIdx.x] = 0;
  __syncthreads();
  int* __restrict__ cnt = cnt8 + (size_t)(blockIdx.x & 7) * M;
  for (int e = blockIdx.x * 256 + threadIdx.x; e < n_edges; e += NBLK * 256) {
    const int r = rows[e];
    atomicAdd(&cnt[r], 1);
    atomicAdd(&lcnt[grp_of(r, gmagic)], 1);
  }
  __syncthreads();
  if (threadIdx.x < 8) cntT[threadIdx.x * NBLK + blockIdx.x] = lcnt[threadIdx.x];
}

// ---------- sum the 8 replicas; per-block totals for the hierarchical scan ----
__global__ __launch_bounds__(256) void sumcnt_kernel(
    const int* __restrict__ cnt8, int* __restrict__ cnts,
    int* __restrict__ bsum, int M) {
  __shared__ int wred[4];
  const int i = blockIdx.x * 256 + threadIdx.x;
  int s = 0;
  if (i < M) {
#pragma unroll
    for (int k = 0; k < 8; ++k) s += cnt8[(size_t)k * M + i];
    cnts[i] = s;
  }
  int t = s;
#pragma unroll
  for (int off = 32; off; off >>= 1) t += __shfl_down(t, off, 64);
  if ((threadIdx.x & 63) == 0) wred[threadIdx.x >> 6] = t;
  __syncthreads();
  if (threadIdx.x == 0) bsum[blockIdx.x] = wred[0] + wred[1] + wred[2] + wred[3];
}

// ---------- generic small exclusive scan (1 block); outA[n] = total ----------
__global__ __launch_bounds__(1024) void scan_kernel(
    const int* __restrict__ cnt, int* __restrict__ outA,
    int* __restrict__ outB, int n) {
  __shared__ int wsum[16];
  __shared__ int carry_sh;
  const int tid = threadIdx.x;
  const int lane = tid & 63;
  const int wid = tid >> 6;
  if (tid == 0) carry_sh = 0;
  __syncthreads();
  for (int base = 0; base < n; base += 4096) {
    const int i0 = base + tid * 4;
    int4 v = make_int4(0, 0, 0, 0);
    if (i0 + 3 < n) v = *reinterpret_cast<const int4*>(cnt + i0);
    else {
      if (i0     < n) v.x = cnt[i0];
      if (i0 + 1 < n) v.y = cnt[i0 + 1];
      if (i0 + 2 < n) v.z = cnt[i0 + 2];
    }
    const int s1 = v.x, s2 = s1 + v.y, s3 = s2 + v.z, s4 = s3 + v.w;
    int ws = s4;
#pragma unroll
    for (int off = 1; off < 64; off <<= 1) {
      int o = __shfl_up(ws, off, 64);
      if (lane >= off) ws += o;
    }
    if (lane == 63) wsum[wid] = ws;
    __syncthreads();
    if (wid == 0) {
      int t = (lane < 16) ? wsum[lane] : 0;
#pragma unroll
      for (int off = 1; off < 16; off <<= 1) {
        int o = __shfl_up(t, off, 64);
        if (lane >= off) t += o;
      }
      if (lane < 16) wsum[lane] = t;
    }
    __syncthreads();
    const int carry = carry_sh;
    const int tbase = carry + (wid ? wsum[wid - 1] : 0) + ws - s4;  // exclusive
    if (i0     < n) { outA[i0]     = tbase;      outB[i0]     = tbase; }
    if (i0 + 1 < n) { outA[i0 + 1] = tbase + s1; outB[i0 + 1] = tbase + s1; }
    if (i0 + 2 < n) { outA[i0 + 2] = tbase + s2; outB[i0 + 2] = tbase + s2; }
    if (i0 + 3 < n) { outA[i0 + 3] = tbase + s3; outB[i0 + 3] = tbase + s3; }
    __syncthreads();
    if (tid == 0) carry_sh = carry + wsum[15];
    __syncthreads();
  }
  if (tid == 0) outA[n] = carry_sh;
}

// ---------- apply block offsets: row_ptr/cursor = excl-scan(cnts) ----------
__global__ __launch_bounds__(256) void scan_apply_kernel(
    const int* __restrict__ cnts, const int* __restrict__ bofs,
    int* __restrict__ row_ptr, int* __restrict__ cursor, int M) {
  __shared__ int wsum[4];
  const int tid = threadIdx.x;
  const int lane = tid & 63;
  const int wid = tid >> 6;
  const int i = blockIdx.x * 256 + tid;
  const int v = (i < M) ? cnts[i] : 0;
  int s = v;
#pragma unroll
  for (int off = 1; off < 64; off <<= 1) {
    int o = __shfl_up(s, off, 64);
    if (lane >= off) s += o;
  }
  if (lane == 63) wsum[wid] = s;
  __syncthreads();
  int add = 0;
  for (int k = 0; k < wid; ++k) add += wsum[k];
  const int excl = bofs[blockIdx.x] + add + s - v;
  if (i < M) { row_ptr[i] = excl; cursor[i] = excl; }
  if (i == M) row_ptr[M] = bofs[gridDim.x];   // total
}

// ---------- pass 2: partition edges into 8 contiguous group segments ----------
__global__ __launch_bounds__(256) void partition_kernel(
    const int* __restrict__ rows, const int* __restrict__ cols,
    const float* __restrict__ vals, const int* __restrict__ pofsT,
    int2* __restrict__ part, int n_edges, unsigned gmagic) {
  __shared__ int lofs[8];
  if (threadIdx.x < 8) lofs[threadIdx.x] = pofsT[threadIdx.x * NBLK + blockIdx.x];
  __syncthreads();
  for (int e = blockIdx.x * 256 + threadIdx.x; e < n_edges; e += NBLK * 256) {
    const int r = rows[e];
    const int g = grp_of(r, gmagic);
    const int slot = atomicAdd(&lofs[g], 1);
    const unsigned short hb = __half_as_ushort(__float2half_rn(vals[e] * 0.5f));
    int2 rv;
    rv.x = r;
    rv.y = (int)(((unsigned)cols[e] << 15) | ((unsigned)hb >> 1));
    part[slot] = rv;
  }
}

// ---------- pass 3: scatter within XCD-local group (write-merge friendly) ----------
__global__ __launch_bounds__(256) void scatter2_kernel(
    const int2* __restrict__ part, const int* __restrict__ pofsT,
    int* __restrict__ cursor, unsigned* __restrict__ colpack) {
  const int g  = blockIdx.x & 7;
  const int bk = blockIdx.x >> 3;
  const int nb = gridDim.x >> 3;
  const int s0 = pofsT[g * NBLK];
  const int s1 = pofsT[(g + 1) * NBLK];   // g=7 -> pofsT[8*NBLK] = total
  for (int i = s0 + bk * 256 + threadIdx.x; i < s1; i += nb * 256) {
    const int2 rv = part[i];
    const int pos = atomicAdd(&cursor[rv.x], 1);
    colpack[pos] = (unsigned)rv.y;
  }
}

// ---------- SpMM, feature-sliced, per-lane predecode ----------
// 4 slices x 64 features (128B). slice = blockIdx&3 -> XCDs {s, s+4}.
// Each lane predecodes ITS window edge once: opre = col*128 (uint index base,
// wave-uniform payload), vpre = value. Inner loop broadcasts via 2 shfls; the
// lane-private fofs is added AFTER the shfl (bug in prev round: fofs was
// folded in before the shfl, delivering the source lane's feature offset).
__global__ __launch_bounds__(256) void spmm_slice(
    const unsigned short* __restrict__ hin, const int* __restrict__ row_ptr,
    const unsigned* __restrict__ colpack, unsigned short* __restrict__ hout,
    int n_nodes) {
  const int slice = blockIdx.x & 3;
  const int lane = threadIdx.x & 63;
  const int half = lane >> 5;
  const int sub  = lane & 31;
  const int wgid = ((blockIdx.x >> 2) * 256 + threadIdx.x) >> 6;  // node-pair id
  const int node = wgid * 2 + half;
  const bool ok = node < n_nodes;
  int start = 0, end = 0;
  if (ok) { start = row_ptr[node]; end = row_ptr[node + 1]; }

  const unsigned* __restrict__ hinw = reinterpret_cast<const unsigned*>(hin);
  const int fofs = slice * 32 + sub;       // uint index within a 128-uint row
  const int sbase = half << 5;

  float acc0 = 0.f, acc1 = 0.f;

  for (int base = start; base < end; base += 32) {
    const int cnt = min(32, end - base);
    unsigned u = 0;                        // u=0 -> (col=0, val=0) dummy
    if (base + sub < end) u = colpack[base + sub];
    const int opre = (int)((u >> 15) << 7);  // col*128, lane-independent payload
    const float vpre = __half2float(__ushort_as_half((unsigned short)((u & 0x7fffu) << 1)));
    for (int t = 0; t < cnt; t += 8) {
      unsigned hv[8];
      float v[8];
#pragma unroll
      for (int j = 0; j < 8; ++j) {
        const int oj = __shfl(opre, sbase + t + j, 64);
        v[j] = __shfl(vpre, sbase + t + j, 64);
        hv[j] = hinw[(size_t)(unsigned)(oj + fofs)];   // 8 independent 4B gathers
      }
#pragma unroll
      for (int j = 0; j < 8; ++j) {
        acc0 += v[j] * asf(hv[j] << 16);
        acc1 += v[j] * asf(hv[j] & 0xffff0000u);
      }
    }
  }
  if (ok) {
    reinterpret_cast<unsigned*>(hout)[(size_t)node * 128 + fofs] =
        (unsigned)f2bf(acc0) | ((unsigned)f2bf(acc1) << 16);
  }
}

// ---------- W[k][n] fp32 -> WT[n][k] bf16 ----------
__global__ __launch_bounds__(256) void wconv_kernel(
    const float* __restrict__ W, unsigned short* __restrict__ WT) {
  int k = blockIdx.x;
  int n = threadIdx.x;
  WT[(size_t)n * N_D + k] = f2bf(W[(size_t)k * N_D + n]);
}

// ---------- GEMM: H[M,256](bf16) @ W via WT(bf16). A read ONCE per block. ----
// Block 256 thr = 4 waves; wave w: rows [bx*64 + w*16, +16) x cols [0,256).
// B (WT, 128KB) is L2-resident; re-reading it per wave is cheap; A streams once.
template <bool RELU, bool OUT_BF16>
__global__ __launch_bounds__(256) void gemm2(
    const unsigned short* __restrict__ H, const unsigned short* __restrict__ WT,
    void* __restrict__ C, int M) {
  const int wave = threadIdx.x >> 6;
  const int lane = threadIdx.x & 63;
  const int m = lane & 15;
  const int p = lane >> 4;
  const int row0 = blockIdx.x * 64 + wave * 16;

  f32x4 acc[16];
#pragma unroll
  for (int i = 0; i < 16; ++i) acc[i] = (f32x4){0.f, 0.f, 0.f, 0.f};

  const int r = row0 + m;
  const bool rok = r < M;

  for (int k0 = 0; k0 < N_D; k0 += 32) {
    bf16x8 a = {0, 0, 0, 0, 0, 0, 0, 0};
    if (rok) a = *reinterpret_cast<const bf16x8*>(H + (size_t)r * N_D + k0 + p * 8);
#pragma unroll
    for (int nt = 0; nt < 16; ++nt) {
      const bf16x8 b = *reinterpret_cast<const bf16x8*>(
          WT + (size_t)(nt * 16 + m) * N_D + k0 + p * 8);
      acc[nt] = __builtin_amdgcn_mfma_f32_16x16x32_bf16(a, b, acc[nt], 0, 0, 0);
    }
  }

  // C/D layout: col = lane&15 (=m), row = p*4 + rr within the 16x16 tile
#pragma unroll
  for (int nt = 0; nt < 16; ++nt) {
    const int col = nt * 16 + m;
#pragma unroll
    for (int rr = 0; rr < 4; ++rr) {
      const int r2 = row0 + p * 4 + rr;
      if (r2 < M) {
        float vv = acc[nt][rr];
        if (RELU) vv = fmaxf(vv, 0.f);
        if (OUT_BF16)
          ((unsigned short*)C)[(size_t)r2 * N_D + col] = f2bf(vv);
        else
          ((float*)C)[(size_t)r2 * N_D + col] = vv;
      }
    }
  }
}

extern "C" void kernel_launch(void* const* d_in, const int* in_sizes, int n_in,
                              void* d_out, int out_size, void* d_ws, size_t ws_size,
                              hipStream_t stream) {
  const float* x    = (const float*)d_in[0];
  const float* vals = (const float*)d_in[1];
  const float* W0   = (const float*)d_in[2];
  const float* W1   = (const float*)d_in[3];
  const int*   rows = (const int*)d_in[4];
  const int*   cols = (const int*)d_in[5];

  const int n_edges = in_sizes[1];
  const int M = in_sizes[0] / N_D;        // 100000
  const size_t n_feat = (size_t)M * N_D;  // 25.6M elements

  char* ws = (char*)d_ws;
  unsigned short* hA      = (unsigned short*)(ws);                  // 51.2 MB bf16
  unsigned*       colpack = (unsigned*)(ws + 51200000);             // 12.8 MB
  int*            row_ptr = (int*)(ws + 64000000);                  // 400 KB
  int*            cursor  = (int*)(ws + 64400128);                  // 400 KB
  int*            cnt8    = (int*)(ws + 64800256);                  // 3.2 MB
  int*            cnts    = (int*)(ws + 68000384);                  // 400 KB
  int*            bsum    = (int*)(ws + 68400512);                  // 2 KB
  int*            bofs    = (int*)(ws + 68402560);                  // 2 KB
  int*            bscr    = (int*)(ws + 68404608);                  // 2 KB
  int*            cntT    = (int*)(ws + 68406656);                  // 26.9 KB
  int*            pofsT   = (int*)(ws + 68433536);                  // 26.9 KB
  int*            pscr    = (int*)(ws + 68460416);                  // 26.9 KB
  unsigned short* wt      = (unsigned short*)(ws + 68487296);       // 128 KB
  // d_out (102.4 MB fp32) hosts bf16/scratch buffers until the final GEMM:
  unsigned short* hB   = (unsigned short*)d_out;                    // lower 51.2 MB
  unsigned short* xb   = (unsigned short*)d_out + n_feat;           // upper 51.2 MB
  int2*           part = (int2*)((char*)d_out + 51200000);          // 25.6 MB (dead until conv)

  const int Mb = (M + 255) / 256;           // 391
  const int sblocks = 4 * ((M + 7) / 8);    // 4 slices x (8 nodes per block)
  const int gblocks = (M + 63) / 64;
  const int cblocks = (int)(n_feat / 4 + 255) / 256;
  const int rpg = (M + 7) / 8;              // rows per XCD group
  const unsigned gmagic = (unsigned)(((1ULL << 37) + rpg - 1) / (unsigned long long)rpg);

  // --- CSR build (once; reused by all 4 SpMMs) ---
  hipMemsetAsync(cnt8, 0, (size_t)8 * M * sizeof(int), stream);
  count_kernel<<<NBLK, 256, 0, stream>>>(rows, cnt8, cntT, n_edges, gmagic, M);
  sumcnt_kernel<<<Mb, 256, 0, stream>>>(cnt8, cnts, bsum, M);
  scan_kernel<<<1, 1024, 0, stream>>>(bsum, bofs, bscr, Mb);
  scan_apply_kernel<<<Mb, 256, 0, stream>>>(cnts, bofs, row_ptr, cursor, M);
  scan_kernel<<<1, 1024, 0, stream>>>(cntT, pofsT, pscr, 8 * NBLK);
  partition_kernel<<<NBLK, 256, 0, stream>>>(rows, cols, vals, pofsT, part,
                                             n_edges, gmagic);
  scatter2_kernel<<<NBLK, 256, 0, stream>>>(part, pofsT, cursor, colpack);
  conv_kernel<<<cblocks, 256, 0, stream>>>(x, xb, (int)(n_feat / 4));  // after part is dead

  // --- layer 0 ---
  spmm_slice<<<sblocks, 256, 0, stream>>>(xb, row_ptr, colpack, hA, M);  // hA = 0.5*A x
  spmm_slice<<<sblocks, 256, 0, stream>>>(hA, row_ptr, colpack, hB, M);  // hB = 0.5*A hA
  wconv_kernel<<<N_D, N_D, 0, stream>>>(W0, wt);
  gemm2<true, true><<<gblocks, 256, 0, stream>>>(hB, wt, hA, M);         // hA = relu(hB@W0)

  // --- layer 1 ---
  spmm_slice<<<sblocks, 256, 0, stream>>>(hA, row_ptr, colpack, hB, M);
  spmm_slice<<<sblocks, 256, 0, stream>>>(hB, row_ptr, colpack, hA, M);
  wconv_kernel<<<N_D, N_D, 0, stream>>>(W1, wt);
  gemm2<false, false><<<gblocks, 256, 0, stream>>>(hA, wt, d_out, M);    // out fp32
}